// Round 16
// baseline (73.332 us; speedup 1.0000x reference)
//
#include <hip/hip_runtime.h>
#include <hip/hip_bf16.h>

typedef short bf16x8 __attribute__((ext_vector_type(8)));
typedef float f32x4 __attribute__((ext_vector_type(4)));
typedef unsigned short u16;
typedef unsigned int u32;

#define NTOK 5120
#define NSDF 4096

__device__ __forceinline__ float b2f(u16 x){
  u32 u = ((u32)x) << 16; float f; __builtin_memcpy(&f, &u, 4); return f;
}
__device__ __forceinline__ u16 f2b(float f){
  u32 u; __builtin_memcpy(&u, &f, 4);
  return (u16)((u + 0x7fffu + ((u >> 16) & 1u)) >> 16);
}
__device__ __forceinline__ u32 cvtpk(float lo, float hi){
  u32 r;
  asm("v_cvt_pk_bf16_f32 %0, %1, %2" : "=v"(r) : "v"(lo), "v"(hi));
  return r;
}
__device__ __forceinline__ f32x4 mfma16(bf16x8 a, bf16x8 b, f32x4 c){
  return __builtin_amdgcn_mfma_f32_16x16x32_bf16(a, b, c, 0, 0, 0);
}
__device__ __forceinline__ void gld16(const void* g, void* l){
  __builtin_amdgcn_global_load_lds(
      (const __attribute__((address_space(1))) u32*)g,
      (__attribute__((address_space(3))) u32*)l, 16, 0, 0);
}

// ---------------- K1: fused embed + QKV. grid 480 = 80 b x 6 grp. (r15-exact)
__global__ __launch_bounds__(256) void k_qkv(
    const float* __restrict__ cond1, const float* __restrict__ cond2,
    const float* __restrict__ W_emb, const float* __restrict__ b_emb,
    const float* __restrict__ W_c3, const float* __restrict__ b_c3,
    const float* __restrict__ pos,
    const float* __restrict__ WQ, const float* __restrict__ WK,
    const float* __restrict__ WV,
    u16* __restrict__ Xout, u16* __restrict__ Q, u16* __restrict__ K,
    u16* __restrict__ VT)
{
  __shared__ __align__(16) u16 Psh[64][72];
  __shared__ __align__(16) u16 Vsh[4][32][72];
  int bid = blockIdx.x, b = bid / 6, grp = bid % 6;
  int t = threadIdx.x, w = t >> 6, lane = t & 63, l15 = lane & 15, g = lane >> 4;
  bool sdb = (b < 64);

  {
    int nl = t >> 2, sub = t & 3;
    const float* src = sdb ? cond1 : cond2;
    int nn = sdb ? (b * 64 + nl) : (b * 64 + nl - NSDF);
    int g0 = nn >> 8, g1 = (nn >> 4) & 15, g2 = nn & 15;
    const float* sp = src + (g0 * 4 + sub) * 4096 + g1 * 4 * 64 + g2 * 4;
    for (int p1 = 0; p1 < 4; ++p1){
      float4 v = *(const float4*)(sp + p1 * 64);
      ushort4 o;
      o.x = f2b(v.x); o.y = f2b(v.y); o.z = f2b(v.z); o.w = f2b(v.w);
      *(ushort4*)&Psh[nl][sub * 16 + p1 * 4] = o;
    }
  }
  int pair = grp * 4 + w, m = pair >> 3, h = pair & 7;
  const float* wsrc = ((m == 0) ? WQ : ((m == 1) ? WK : WV)) + h * 64 * 32;
  float wscale = (m == 0) ? 0.17677669529663689f * 1.4426950408889634f : 1.0f;
  bf16x8 wb0[2], wb1[2];
  #pragma unroll
  for (int nb = 0; nb < 2; ++nb){
    union { bf16x8 v; u16 s[8]; } u0, u1;
    #pragma unroll
    for (int j = 0; j < 8; ++j){
      u0.s[j] = f2b(wsrc[(g * 8 + j) * 32 + nb * 16 + l15] * wscale);
      u1.s[j] = f2b(wsrc[(32 + g * 8 + j) * 32 + nb * 16 + l15] * wscale);
    }
    wb0[nb] = u0.v;
    wb1[nb] = u1.v;
  }
  __syncthreads();

  const float* Wf = sdb ? W_c3 : W_emb;
  const float* bias = sdb ? b_c3 : b_emb;
  bf16x8 pa0 = *(const bf16x8*)&Psh[w * 16 + l15][g * 8];
  bf16x8 pa1 = *(const bf16x8*)&Psh[w * 16 + l15][32 + g * 8];
  u16 xv[4][4];
  #pragma unroll
  for (int nb = 0; nb < 4; ++nb){
    union { bf16x8 v; u16 s[8]; } e0, e1;
    const float* wr = Wf + (nb * 16 + l15) * 64;
    #pragma unroll
    for (int j = 0; j < 8; ++j){
      e0.s[j] = f2b(wr[g * 8 + j]);
      e1.s[j] = f2b(wr[32 + g * 8 + j]);
    }
    f32x4 acc = {0.f, 0.f, 0.f, 0.f};
    acc = mfma16(pa0, e0.v, acc);
    acc = mfma16(pa1, e1.v, acc);
    int d = nb * 16 + l15;
    float bs = bias[d];
    #pragma unroll
    for (int r = 0; r < 4; ++r){
      int tok = b * 64 + w * 16 + g * 4 + r;
      u16 xb = f2b(acc[r] + bs + pos[tok * 64 + d]);
      xv[nb][r] = xb;
      if (grp == 0) Xout[tok * 64 + d] = xb;
    }
  }
  __syncthreads();
  #pragma unroll
  for (int nb = 0; nb < 4; ++nb)
    #pragma unroll
    for (int r = 0; r < 4; ++r)
      Psh[w * 16 + g * 4 + r][nb * 16 + l15] = xv[nb][r];
  __syncthreads();

  bf16x8 a0[4], a1[4];
  #pragma unroll
  for (int ms = 0; ms < 4; ++ms){
    a0[ms] = *(const bf16x8*)&Psh[ms * 16 + l15][g * 8];
    a1[ms] = *(const bf16x8*)&Psh[ms * 16 + l15][32 + g * 8];
  }
  if (grp < 4){
    #pragma unroll
    for (int nb = 0; nb < 2; ++nb){
      int e = nb * 16 + l15;
      #pragma unroll
      for (int ms = 0; ms < 4; ++ms){
        f32x4 acc = {0.f, 0.f, 0.f, 0.f};
        acc = mfma16(a0[ms], wb0[nb], acc);
        acc = mfma16(a1[ms], wb1[nb], acc);
        #pragma unroll
        for (int r = 0; r < 4; ++r){
          int n = b * 64 + ms * 16 + g * 4 + r;
          u16 v = f2b(acc[r]);
          if (m == 0) Q[(h * NTOK + n) * 32 + e] = v;
          else        K[(h * NTOK + n) * 32 + e] = v;
        }
      }
    }
  } else {
    #pragma unroll
    for (int nb = 0; nb < 2; ++nb){
      int e = nb * 16 + l15;
      #pragma unroll
      for (int ms = 0; ms < 4; ++ms){
        f32x4 acc = {0.f, 0.f, 0.f, 0.f};
        acc = mfma16(a0[ms], wb0[nb], acc);
        acc = mfma16(a1[ms], wb1[nb], acc);
        #pragma unroll
        for (int r = 0; r < 4; ++r)
          Vsh[w][e][ms * 16 + g * 4 + r] = f2b(acc[r]);
      }
    }
    __syncthreads();
    int hl = t >> 6, e = (t >> 1) & 31, part = t & 1;
    int hglob = (grp - 4) * 4 + hl;
    const u16* src = &Vsh[hl][e][part * 32];
    u16* dst = VT + (size_t)(hglob * 32 + e) * NTOK + b * 64 + part * 32;
    #pragma unroll
    for (int j = 0; j < 4; ++j)
      *(uint4*)(dst + j * 8) = *(const uint4*)(src + j * 8);
  }
}

// ---------------- K2: flash attention, TRIPLE-buffer / ONE barrier per kt.
// Hazard proof: stage at iter kt is issued AFTER barrier(kt); it targets
// buf[(kt+2)%3], last read at iter kt-1 — and barrier(kt) postdates all
// compute(kt-1). stage(kt+1) targets buf[cur_kt], protected by barrier(kt+1).
// vmcnt(4): <=4 outstanding => own tile-kt loads landed (tile kt+1 in flight).
// Blocks >= 1280 convert Wto/Wcb (consumed by LATER kernels) and exit.
__global__ __launch_bounds__(256) void k_attn(
    const u16* __restrict__ Q, const u16* __restrict__ K, const u16* __restrict__ VT,
    u16* __restrict__ Opb, float* __restrict__ lpart,
    const float* __restrict__ W_out, const float* __restrict__ Wc,
    u16* __restrict__ Wto, u16* __restrict__ Wcb)
{
  __shared__ __align__(16) u16 Ksh[3][128 * 32];
  __shared__ __align__(16) u16 Vsh[3][32 * 128];
  int bid = blockIdx.x;
  int t = threadIdx.x;
  if (bid >= 1280){
    int gid = (bid - 1280) * 256 + t;
    for (int i = gid; i < 16384; i += 2048){
      int k2 = i >> 6, d = i & 63;
      Wto[d * 256 + k2] = f2b(W_out[i]);
    }
    for (int i = gid; i < 20480; i += 2048) Wcb[i] = f2b(Wc[i]);
    return;
  }
  int x = bid & 7;
  int inner = bid >> 3;
  int qb = inner % 40;
  int p = x + 8 * (inner / 40);
  int sp = p >> 3, h = p & 7;
  int w = t >> 6, lane = t & 63, l15 = lane & 15, g = lane >> 4;
  int q0w = qb * 128 + w * 32;
  int kb = sp * 1280;
  int wb = w * 512;

  int rho0 = t >> 2, cpK = t & 3;
  int key0 = (rho0 & 0x60) | ((rho0 & 0x0C) << 1) | ((rho0 & 0x10) >> 2) | (rho0 & 3);
  int clogK = cpK ^ (rho0 & 3);
  const uint4* kg0 = (const uint4*)(K + (size_t)(h * NTOK + kb + key0) * 32 + clogK * 8);
  const uint4* kg1 = (const uint4*)(K + (size_t)(h * NTOK + kb + key0 + 64) * 32 + clogK * 8);
  int eV = t >> 4, cpV = t & 15;
  int clogV = cpV ^ eV;
  const uint4* vg0 = (const uint4*)(VT + (size_t)(h * 32 + eV) * NTOK + kb + clogV * 8);
  const uint4* vg1 = (const uint4*)(VT + (size_t)(h * 32 + eV + 16) * NTOK + kb + clogV * 8);

  bf16x8 qf0 = *(const bf16x8*)(Q + (size_t)(h * NTOK + q0w + l15) * 32 + g * 8);
  bf16x8 qf1 = *(const bf16x8*)(Q + (size_t)(h * NTOK + q0w + 16 + l15) * 32 + g * 8);

  union { u16 s[8]; bf16x8 v; } one8;
  #pragma unroll
  for (int j = 0; j < 8; ++j) one8.s[j] = 0x3F80;
  bf16x8 ones = one8.v;

  f32x4 oc[2][2];
  for (int u = 0; u < 2; ++u) for (int eb = 0; eb < 2; ++eb) oc[u][eb] = (f32x4){0.f,0.f,0.f,0.f};
  f32x4 als0 = {0.f,0.f,0.f,0.f}, als1 = {0.f,0.f,0.f,0.f};

  int kf_base = l15 * 32 + ((g ^ (l15 & 3)) * 8);

  // prologue: stage tiles 0 and 1
  gld16(kg0, &Ksh[0][wb]);
  gld16(kg1, &Ksh[0][wb + 2048]);
  gld16(vg0, &Vsh[0][wb]);
  gld16(vg1, &Vsh[0][wb + 2048]);
  gld16(kg0 + 512, &Ksh[1][wb]);
  gld16(kg1 + 512, &Ksh[1][wb + 2048]);
  gld16(vg0 + 16,  &Vsh[1][wb]);
  gld16(vg1 + 16,  &Vsh[1][wb + 2048]);

  int cur = 0, stg = 2;
  for (int kt = 0; kt < 10; ++kt){
    if (kt < 8){
      asm volatile("s_waitcnt vmcnt(4)" ::: "memory");   // own tile-kt loads landed
    } else {
      asm volatile("s_waitcnt vmcnt(0)" ::: "memory");
    }
    __builtin_amdgcn_sched_barrier(0);
    __builtin_amdgcn_s_barrier();        // all waves: tile-kt landed, compute(kt-1) done
    __builtin_amdgcn_sched_barrier(0);
    if (kt < 8){
      gld16(kg0 + (kt + 2) * 512, &Ksh[stg][wb]);
      gld16(kg1 + (kt + 2) * 512, &Ksh[stg][wb + 2048]);
      gld16(vg0 + (kt + 2) * 16,  &Vsh[stg][wb]);
      gld16(vg1 + (kt + 2) * 16,  &Vsh[stg][wb + 2048]);
    }
    const u16* kB = &Ksh[cur][0];
    const u16* vB = &Vsh[cur][0];
    #pragma unroll
    for (int ks = 0; ks < 4; ++ks){
      f32x4 z = {0.f,0.f,0.f,0.f};
      bf16x8 kf0 = *(const bf16x8*)(kB + kf_base + ks * 1024);
      bf16x8 kf1 = *(const bf16x8*)(kB + kf_base + ks * 1024 + 512);
      f32x4 s0a = mfma16(kf0, qf0, z);
      f32x4 s1a = mfma16(kf1, qf0, z);
      f32x4 s0b = mfma16(kf0, qf1, z);
      f32x4 s1b = mfma16(kf1, qf1, z);
      int vf_off = l15 * 128 + (((ks * 4 + g) ^ l15) * 8);
      bf16x8 vf0 = *(const bf16x8*)(vB + vf_off);
      bf16x8 vf1 = *(const bf16x8*)(vB + vf_off + 2048);
      float pa0 = __builtin_amdgcn_exp2f(s0a[0]);
      float pa1 = __builtin_amdgcn_exp2f(s0a[1]);
      float pa2 = __builtin_amdgcn_exp2f(s0a[2]);
      float pa3 = __builtin_amdgcn_exp2f(s0a[3]);
      float pa4 = __builtin_amdgcn_exp2f(s1a[0]);
      float pa5 = __builtin_amdgcn_exp2f(s1a[1]);
      float pa6 = __builtin_amdgcn_exp2f(s1a[2]);
      float pa7 = __builtin_amdgcn_exp2f(s1a[3]);
      union { bf16x8 v; u32 wd[4]; } pua;
      pua.wd[0] = cvtpk(pa0, pa1); pua.wd[1] = cvtpk(pa2, pa3);
      pua.wd[2] = cvtpk(pa4, pa5); pua.wd[3] = cvtpk(pa6, pa7);
      float pb0 = __builtin_amdgcn_exp2f(s0b[0]);
      float pb1 = __builtin_amdgcn_exp2f(s0b[1]);
      float pb2 = __builtin_amdgcn_exp2f(s0b[2]);
      float pb3 = __builtin_amdgcn_exp2f(s0b[3]);
      float pb4 = __builtin_amdgcn_exp2f(s1b[0]);
      float pb5 = __builtin_amdgcn_exp2f(s1b[1]);
      float pb6 = __builtin_amdgcn_exp2f(s1b[2]);
      float pb7 = __builtin_amdgcn_exp2f(s1b[3]);
      union { bf16x8 v; u32 wd[4]; } pub;
      pub.wd[0] = cvtpk(pb0, pb1); pub.wd[1] = cvtpk(pb2, pb3);
      pub.wd[2] = cvtpk(pb4, pb5); pub.wd[3] = cvtpk(pb6, pb7);
      oc[0][0] = mfma16(pua.v, vf0, oc[0][0]);
      oc[0][1] = mfma16(pua.v, vf1, oc[0][1]);
      oc[1][0] = mfma16(pub.v, vf0, oc[1][0]);
      oc[1][1] = mfma16(pub.v, vf1, oc[1][1]);
      als0 = mfma16(pua.v, ones, als0);      // row-sums, k-reduced by MFMA
      als1 = mfma16(pub.v, ones, als1);
    }
    cur = (cur == 2) ? 0 : cur + 1;
    stg = (stg == 2) ? 0 : stg + 1;
  }

  u16* opp = Opb + ((size_t)(sp * 8 + h) * NTOK + q0w) * 32;
  for (int u = 0; u < 2; ++u)
    for (int eb = 0; eb < 2; ++eb)
      for (int r = 0; r < 4; ++r)
        opp[(u * 16 + 4 * g + r) * 32 + eb * 16 + l15] = f2b(oc[u][eb][r]);
  if (l15 == 0){
    float* lp = lpart + (size_t)(sp * 8 + h) * NTOK + q0w;
    #pragma unroll
    for (int r = 0; r < 4; ++r){
      lp[4 * g + r]      = als0[r];
      lp[16 + 4 * g + r] = als1[r];
    }
  }
}

// ---------------- K3: fused split-K merge + Xn = O @ W_out + X + LN partials.
__global__ __launch_bounds__(64) void k_xn(
    const u16* __restrict__ Opb, const float* __restrict__ lpart,
    const u16* __restrict__ Wto, const u16* __restrict__ X,
    float* __restrict__ Xn, float* __restrict__ partials)
{
  int b = blockIdx.x, lane = threadIdx.x, l15 = lane & 15, g = lane >> 4;
  int n0 = b * 16;
  int n = n0 + l15;
  f32x4 acc[4];
  #pragma unroll
  for (int nb = 0; nb < 4; ++nb) acc[nb] = (f32x4){0.f,0.f,0.f,0.f};
  #pragma unroll
  for (int ks = 0; ks < 8; ++ks){               // ks == head
    float l = lpart[(size_t)(0 * 8 + ks) * NTOK + n]
            + lpart[(size_t)(1 * 8 + ks) * NTOK + n]
            + lpart[(size_t)(2 * 8 + ks) * NTOK + n]
            + lpart[(size_t)(3 * 8 + ks) * NTOK + n];
    float rl = 1.0f / l;
    float ac0 = 0.f, ac1 = 0.f, ac2 = 0.f, ac3 = 0.f;
    float ac4 = 0.f, ac5 = 0.f, ac6 = 0.f, ac7 = 0.f;
    #pragma unroll
    for (int sp = 0; sp < 4; ++sp){
      union { bf16x8 v; u16 s[8]; } u;
      u.v = *(const bf16x8*)(Opb + (((size_t)(sp * 8 + ks) * NTOK + n) << 5) + g * 8);
      ac0 += b2f(u.s[0]); ac1 += b2f(u.s[1]); ac2 += b2f(u.s[2]); ac3 += b2f(u.s[3]);
      ac4 += b2f(u.s[4]); ac5 += b2f(u.s[5]); ac6 += b2f(u.s[6]); ac7 += b2f(u.s[7]);
    }
    union { bf16x8 v; u32 wd[4]; } mm;
    mm.wd[0] = cvtpk(ac0 * rl, ac1 * rl);
    mm.wd[1] = cvtpk(ac2 * rl, ac3 * rl);
    mm.wd[2] = cvtpk(ac4 * rl, ac5 * rl);
    mm.wd[3] = cvtpk(ac6 * rl, ac7 * rl);
    bf16x8 av = mm.v;
    #pragma unroll
    for (int nb = 0; nb < 4; ++nb){
      bf16x8 bb = *(const bf16x8*)(Wto + (nb * 16 + l15) * 256 + ks * 32 + g * 8);
      acc[nb] = mfma16(av, bb, acc[nb]);
    }
  }
  float s1 = 0.f, s2 = 0.f;
  #pragma unroll
  for (int nb = 0; nb < 4; ++nb){
    int d = nb * 16 + l15;
    #pragma unroll
    for (int r = 0; r < 4; ++r){
      int nn = n0 + g * 4 + r;
      float v = acc[nb][r] + b2f(X[nn * 64 + d]);
      Xn[nn * 64 + d] = v;
      s1 += v; s2 += v * v;
    }
  }
  for (int off = 1; off < 64; off <<= 1){
    s1 += __shfl_xor(s1, off);
    s2 += __shfl_xor(s2, off);
  }
  if (lane == 0){
    partials[b * 2]     = s1;
    partials[b * 2 + 1] = s2;
  }
}

// ---------------- K4: global LN stats (320 partials) + gamma/beta + conv2d -> f32
__global__ __launch_bounds__(256) void k_out(
    const float* __restrict__ Xn, const float* __restrict__ partials,
    const float* __restrict__ gamma, const float* __restrict__ beta,
    const u16* __restrict__ Wcb, const float* __restrict__ bc,
    float* __restrict__ out)
{
  __shared__ float redA[8];
  __shared__ float murs2[2];
  __shared__ __align__(16) float Xs[80 * 16];
  int bid = blockIdx.x, t = threadIdx.x, w = t >> 6, lane = t & 63;
  int hh = bid >> 2, wq = (bid & 3) * 16;
  float s1 = 0.f, s2 = 0.f;
  for (int i = t; i < 320; i += 256){
    s1 += partials[2 * i];
    s2 += partials[2 * i + 1];
  }
  for (int off = 1; off < 64; off <<= 1){ s1 += __shfl_xor(s1, off); s2 += __shfl_xor(s2, off); }
  if (lane == 0){ redA[w * 2] = s1; redA[w * 2 + 1] = s2; }
  __syncthreads();
  if (t == 0){
    float S1 = redA[0] + redA[2] + redA[4] + redA[6];
    float S2 = redA[1] + redA[3] + redA[5] + redA[7];
    const float inv = 1.0f / 327680.0f;
    float mu = S1 * inv;
    murs2[0] = mu;
    murs2[1] = rsqrtf(S2 * inv - mu * mu + 1e-5f);
  }
  __syncthreads();
  float mu = murs2[0], rs = murs2[1];
  for (int i = t; i < 1280; i += 256){
    int c = i >> 4, ww = wq + (i & 15);
    int idx = (c * 64 + hh) * 64 + ww;
    Xs[i] = (Xn[idx] - mu) * rs * gamma[idx] + beta[idx];
  }
  __syncthreads();
  int o = t;
  const u16* wr = Wcb + o * 80;
  f32x4 acc4[4];
  for (int k = 0; k < 4; ++k) acc4[k] = (f32x4){0.f,0.f,0.f,0.f};
  for (int c = 0; c < 80; ++c){
    float wt = b2f(wr[c]);
    for (int k = 0; k < 4; ++k)
      acc4[k] += (*(const f32x4*)&Xs[c * 16 + k * 4]) * wt;
  }
  float bb = bc[o];
  for (int k = 0; k < 4; ++k)
    for (int j = 0; j < 4; ++j)
      out[o * 4096 + hh * 64 + wq + k * 4 + j] = acc4[k][j] + bb;
}

extern "C" void kernel_launch(void* const* d_in, const int* in_sizes, int n_in,
                              void* d_out, int out_size, void* d_ws, size_t ws_size,
                              hipStream_t stream) {
  const float* cond1 = (const float*)d_in[0];
  const float* cond2 = (const float*)d_in[1];
  const float* W_emb = (const float*)d_in[2];
  const float* b_emb = (const float*)d_in[3];
  const float* W_c3  = (const float*)d_in[4];
  const float* b_c3  = (const float*)d_in[5];
  const float* pos   = (const float*)d_in[6];
  const float* WQ    = (const float*)d_in[7];
  const float* WK    = (const float*)d_in[8];
  const float* WV    = (const float*)d_in[9];
  const float* W_out = (const float*)d_in[10];
  const float* gamma = (const float*)d_in[11];
  const float* beta  = (const float*)d_in[12];
  const float* Wc    = (const float*)d_in[13];
  const float* bc    = (const float*)d_in[14];
  float* out = (float*)d_out;
  char* ws = (char*)d_ws;

  u16*   X   = (u16*)(ws);                    // 655,360
  u16*   Q   = (u16*)(ws +   655360);         // 2,621,440
  u16*   Kq  = (u16*)(ws +  3276800);         // 2,621,440
  u16*   VT  = (u16*)(ws +  5898240);         // 2,621,440
  float* Xn  = (float*)(ws + 11141120);       // 1,310,720
  u16*   Wto = (u16*)(ws + 12550144);         // 32,768
  float* partials = (float*)(ws + 12582912);  // 2,560
  u16*   Wcb    = (u16*)(ws + 12601856);      // 40,960
  u16*   Opb    = (u16*)(ws + 12648448);      // 4*8*5120*32*2 = 10,485,760
  float* lpart  = (float*)(ws + 23134208);    // 4*8*5120*4    = 655,360 (end 23,789,568)

  k_qkv<<<480, 256, 0, stream>>>(cond1, cond2, W_emb, b_emb, W_c3, b_c3, pos,
                                 WQ, WK, WV, X, Q, Kq, VT);
  k_attn<<<1288, 256, 0, stream>>>(Q, Kq, VT, Opb, lpart, W_out, Wc, Wto, Wcb);
  k_xn<<<320, 64, 0, stream>>>(Opb, lpart, Wto, X, Xn, partials);
  k_out<<<256, 256, 0, stream>>>(Xn, partials, gamma, beta, Wcb, bc, out);
}